// Round 7
// baseline (688.088 us; speedup 1.0000x reference)
//
#include <hip/hip_runtime.h>
#include <math.h>

#define TOKENS 4096
#define BATCH 64

typedef __attribute__((ext_vector_type(8))) short bf16x8;
typedef __attribute__((ext_vector_type(4))) float f32x4;
union U4B { uint4 u; bf16x8 b; };

__device__ __forceinline__ float wsum(float v) {
#pragma unroll
  for (int m = 32; m >= 1; m >>= 1) v += __shfl_xor(v, m);
  return v;
}
__device__ __forceinline__ unsigned short f2bf(float f) {
  unsigned u = __float_as_uint(f);
  u += 0x7fffu + ((u >> 16) & 1u);
  return (unsigned short)(u >> 16);
}
__device__ __forceinline__ float sigmf(float x) { return 1.f / (1.f + expf(-x)); }

// ================= K_PRE: LN->x | slot-init+qw0 | weight transposes ==========
// grid 66240 x 256:
//   [0, 65536)        : LN(inputs) -> x bf16 (4 rows/block)
//   [65536, 65600)    : per-n slot init + qw for iteration 0 (raw Wq/Wk)
//   [65600, 66240)    : 640 32x32 transpose tiles over the 6 weight matrices
__global__ __launch_bounds__(256) void k_pre(
    const float* __restrict__ in, const float* __restrict__ lin_g,
    const float* __restrict__ lin_b, unsigned* __restrict__ x,
    const float* __restrict__ smu, const float* __restrict__ slsig,
    const float* __restrict__ noise, float* __restrict__ slots,
    const float* __restrict__ lsl_g, const float* __restrict__ lsl_b,
    const float* __restrict__ Wq, const float* __restrict__ Wk,
    unsigned* __restrict__ qwb,
    const float* __restrict__ Wv, const float* __restrict__ Wih,
    const float* __restrict__ Whh, const float* __restrict__ W1,
    const float* __restrict__ W2,
    float* __restrict__ WqT, float* __restrict__ WvT, float* __restrict__ WihT,
    float* __restrict__ WhhT, float* __restrict__ W1T, float* __restrict__ W2T) {
  int bid = blockIdx.x, tid = threadIdx.x;
  if (bid < 65536) {
    int row = bid * 4 + (tid >> 6);
    int lane = tid & 63;
    const float* p = in + (size_t)row * 256 + lane * 4;
    float4 v = *(const float4*)p;
    float s  = wsum(v.x + v.y + v.z + v.w);
    float sq = wsum(v.x * v.x + v.y * v.y + v.z * v.z + v.w * v.w);
    float mu = s * (1.f / 256.f);
    float var = sq * (1.f / 256.f) - mu * mu;
    float rs = rsqrtf(var + 1e-5f);
    float4 gg = *(const float4*)(lin_g + lane * 4);
    float4 bb = *(const float4*)(lin_b + lane * 4);
    float y0 = (v.x - mu) * rs * gg.x + bb.x;
    float y1 = (v.y - mu) * rs * gg.y + bb.y;
    float y2 = (v.z - mu) * rs * gg.z + bb.z;
    float y3 = (v.w - mu) * rs * gg.w + bb.w;
    uint2 o;
    o.x = (unsigned)f2bf(y0) | ((unsigned)f2bf(y1) << 16);
    o.y = (unsigned)f2bf(y2) | ((unsigned)f2bf(y3) << 16);
    *(uint2*)(x + (size_t)row * 128 + lane * 2) = o;
    return;
  }
  if (bid < 65536 + 64) {
    __shared__ float sl_s[8][256];
    __shared__ float tmp[256];
    __shared__ float qv[256];
    __shared__ float red2[8];
    int n = bid - 65536;
    for (int i = tid; i < 2048; i += 256) {
      float v = smu[i] + expf(slsig[i]) * noise[(size_t)n * 2048 + i];
      slots[(size_t)n * 2048 + i] = v;
      sl_s[i >> 8][i & 255] = v;
    }
    __syncthreads();
    for (int s = 0; s < 8; ++s) {
      float v = sl_s[s][tid];
      float ps = wsum(v), pq = wsum(v * v);
      if ((tid & 63) == 0) { red2[tid >> 6] = ps; red2[4 + (tid >> 6)] = pq; }
      __syncthreads();
      float sum = red2[0] + red2[1] + red2[2] + red2[3];
      float sqq = red2[4] + red2[5] + red2[6] + red2[7];
      float mu = sum * (1.f / 256.f);
      float var = sqq * (1.f / 256.f) - mu * mu;
      float rs = rsqrtf(var + 1e-5f);
      tmp[tid] = (v - mu) * rs * lsl_g[tid] + lsl_b[tid];
      __syncthreads();
      float a = 0.f;
      for (int d = 0; d < 256; ++d) a += tmp[d] * Wq[(size_t)tid * 256 + d];
      qv[tid] = a;
      __syncthreads();
      float c = 0.f;
      for (int e = 0; e < 256; ++e) c += qv[e] * Wk[(size_t)e * 256 + tid];
      c *= 0.0625f;
      __syncthreads();
      tmp[tid] = c;
      __syncthreads();
      if (tid < 128)
        qwb[((size_t)n * 8 + s) * 128 + tid] =
            (unsigned)f2bf(tmp[2 * tid]) | ((unsigned)f2bf(tmp[2 * tid + 1]) << 16);
      __syncthreads();
    }
    return;
  }
  {
    __shared__ float t[32][33];
    int t2 = bid - 65600;
    const float* S; float* D; int R; int tile;
    if (t2 < 64)       { S = Wq;  D = WqT;  R = 256; tile = t2; }
    else if (t2 < 128) { S = Wv;  D = WvT;  R = 256; tile = t2 - 64; }
    else if (t2 < 192) { S = W1;  D = W1T;  R = 256; tile = t2 - 128; }
    else if (t2 < 256) { S = W2;  D = W2T;  R = 256; tile = t2 - 192; }
    else if (t2 < 448) { S = Wih; D = WihT; R = 768; tile = t2 - 256; }
    else               { S = Whh; D = WhhT; R = 768; tile = t2 - 448; }
    int rt = R >> 5;
    int r0 = (tile % rt) * 32, c0 = (tile / rt) * 32;
    int ci = tid & 31, r8 = tid >> 5;
#pragma unroll
    for (int k = 0; k < 4; ++k) {
      int r = r8 + k * 8;
      t[r][ci] = S[(size_t)(r0 + r) * 256 + c0 + ci];
    }
    __syncthreads();
#pragma unroll
    for (int k = 0; k < 4; ++k) {
      int r = r8 + k * 8;
      D[(size_t)(c0 + r) * R + r0 + ci] = t[ci][r];
    }
  }
}

// ========== K_TRX: bf16 transpose x[n][t][d] -> xT[n][d][t] ==================
__global__ __launch_bounds__(256) void k_trx(const unsigned* __restrict__ x,
                                             unsigned* __restrict__ xT) {
  __shared__ unsigned u[128][65];
  int tt = blockIdx.x, dt = blockIdx.y, n = blockIdx.z;
  int tid = threadIdx.x;
  int t0 = tt * 128, c0 = dt * 64;
  {
    int row = tid >> 1, half = tid & 1;
    const unsigned* sp = x + ((size_t)n * 4096 + t0 + row) * 128 + c0 + half * 32;
    unsigned* dr = &u[row][half * 32];
#pragma unroll
    for (int j = 0; j < 8; ++j) {
      uint4 vv = *(const uint4*)(sp + j * 4);
      dr[j * 4 + 0] = vv.x;
      dr[j * 4 + 1] = vv.y;
      dr[j * 4 + 2] = vv.z;
      dr[j * 4 + 3] = vv.w;
    }
  }
  __syncthreads();
#pragma unroll
  for (int p = 0; p < 8; ++p) {
    int dl = p * 16 + (tid >> 4);
    int c = dl >> 1, hi = dl & 1;
    unsigned o[4];
#pragma unroll
    for (int k = 0; k < 4; ++k) {
      int j = (tid & 15) * 4 + k;
      unsigned u0 = u[2 * j][c], u1 = u[2 * j + 1][c];
      unsigned h0 = hi ? (u0 >> 16) : (u0 & 0xffffu);
      unsigned h1 = hi ? (u1 >> 16) : (u1 & 0xffffu);
      o[k] = h0 | (h1 << 16);
    }
    unsigned* dp = xT + ((size_t)n * 256 + dt * 128 + dl) * 2048 + tt * 64 + (tid & 15) * 4;
    *(uint4*)dp = *(uint4*)&o[0];
  }
}

// ========== K_ATT: QK^T (MFMA) + local softmax + PV (MFMA), per chunk ========
// grid (8 chunks of 512 t, 64 n), 256 threads. Outputs per (n,ch):
//   stats[n][s][ch] = (M_local, S_local);  axp[n][ch][s][d] = sum exp(l-M_local)*x
__global__ __launch_bounds__(256) void k_att(const unsigned* __restrict__ x,
                                             const unsigned* __restrict__ xT,
                                             const unsigned* __restrict__ qwb,
                                             float2* __restrict__ stats,
                                             float* __restrict__ axp) {
  __shared__ float ls[8][520];
  __shared__ unsigned at2[8][264];
  __shared__ float MS[8];
  int ch = blockIdx.x, n = blockIdx.y;
  int tid = threadIdx.x, wv = tid >> 6, l = tid & 63;
  int col = l & 15, g = l >> 4;
  uint4 a[8];
  {
    const unsigned* ap = qwb + ((size_t)n * 8 + (l & 7)) * 128 + g * 4;
#pragma unroll
    for (int kk = 0; kk < 8; ++kk) a[kk] = *(const uint4*)(ap + kk * 16);
  }
  // phase A: QK^T -> ls
  int tb = ch * 512 + wv * 128;
#pragma unroll
  for (int tt = 0; tt < 8; ++tt) {
    int t0 = tb + tt * 16;
    const unsigned* bp = x + ((size_t)n * 4096 + t0 + col) * 128 + g * 4;
    f32x4 acc = {0.f, 0.f, 0.f, 0.f};
#pragma unroll
    for (int kk = 0; kk < 8; ++kk) {
      U4B aa, bb;
      aa.u = a[kk];
      bb.u = *(const uint4*)(bp + kk * 16);
      acc = __builtin_amdgcn_mfma_f32_16x16x32_bf16(aa.b, bb.b, acc, 0, 0, 0);
    }
    if (g < 2) {
#pragma unroll
      for (int r = 0; r < 4; ++r) ls[g * 4 + r][wv * 128 + tt * 16 + col] = acc[r];
    }
  }
  __syncthreads();
  // phase B: local (M,S) per slot
  int s = tid >> 5, q = tid & 31;
  {
    float vv[16];
    float M = -3.4e38f;
#pragma unroll
    for (int j = 0; j < 16; ++j) {
      vv[j] = ls[s][q + j * 32];
      M = fmaxf(M, vv[j]);
    }
#pragma unroll
    for (int m = 16; m >= 1; m >>= 1) M = fmaxf(M, __shfl_xor(M, m));
    float S = 0.f;
#pragma unroll
    for (int j = 0; j < 16; ++j) S += expf(vv[j] - M);
#pragma unroll
    for (int m = 16; m >= 1; m >>= 1) S += __shfl_xor(S, m);
    if (q == 0) {
      stats[((size_t)n * 8 + s) * 8 + ch] = make_float2(M, S);
      MS[s] = M;
    }
  }
  __syncthreads();
  // phase C: at2 = packed bf16 exp(l - M_local)  (strided pairs: conflict-free)
  {
    float M = MS[s];
#pragma unroll
    for (int j = 0; j < 8; ++j) {
      int w = q + j * 32;
      float e0 = expf(ls[s][2 * w] - M);
      float e1 = expf(ls[s][2 * w + 1] - M);
      at2[s][w] = (unsigned)f2bf(e0) | ((unsigned)f2bf(e1) << 16);
    }
  }
  __syncthreads();
  // phase D: PV from LDS attn + global xT
  const unsigned* apl = &at2[l & 7][0];
#pragma unroll
  for (int dt = 0; dt < 4; ++dt) {
    int d0 = (wv * 4 + dt) * 16;
    const unsigned* bp = xT + ((size_t)n * 256 + d0 + col) * 2048 + ch * 256 + g * 4;
    f32x4 acc = {0.f, 0.f, 0.f, 0.f};
#pragma unroll
    for (int kk = 0; kk < 8; ++kk) {
      U4B aa, bb;
      aa.u = *(const uint4*)(apl + kk * 16 + g * 4);
      bb.u = *(const uint4*)(bp + kk * 16);
      acc = __builtin_amdgcn_mfma_f32_16x16x32_bf16(aa.b, bb.b, acc, 0, 0, 0);
    }
    if (g < 2) {
#pragma unroll
      for (int r = 0; r < 4; ++r)
        axp[(((size_t)n * 8 + ch) * 8 + g * 4 + r) * 256 + d0 + col] = acc[r];
    }
  }
}

// ========== K_UPDATE3: combine chunks, Wv, GRU, LN, MLP (+ next-iter qw) =====
// grid (64, 2), 512 threads, 4 slots/block
__global__ __launch_bounds__(512) void k_update3(
    const float* __restrict__ axp, const float2* __restrict__ stats,
    const float* __restrict__ slots_in,
    const float* __restrict__ WvT, const float* __restrict__ WihT,
    const float* __restrict__ WhhT, const float* __restrict__ b_ih,
    const float* __restrict__ b_hh, const float* __restrict__ W1T,
    const float* __restrict__ b1, const float* __restrict__ W2T,
    const float* __restrict__ b2, const float* __restrict__ lml_g,
    const float* __restrict__ lml_b, const float* __restrict__ lsl_g,
    const float* __restrict__ lsl_b, const float* __restrict__ WqT,
    const float* __restrict__ Wk, unsigned* __restrict__ qwb, int doQw,
    float* __restrict__ slots_out) {
  __shared__ float ax[4][256];
  __shared__ float sp[4][256];
  __shared__ float upd[4][256];
  __shared__ float gi[4][768];
  __shared__ float gh[4][768];
  __shared__ float sn[4][256];
  __shared__ float lnv[4][256];
  __shared__ float hid[4][256];
  __shared__ float red[16];
  __shared__ float wch[4][8];
  __shared__ float inv4[4];
  int n = blockIdx.x, sg = blockIdx.y * 4;
  int tid = threadIdx.x;
  // 0. softmax chunk-combine weights
  if (tid < 4) {
    const float2* st = stats + ((size_t)n * 8 + sg + tid) * 8;
    float M = -3.4e38f;
#pragma unroll
    for (int c = 0; c < 8; ++c) M = fmaxf(M, st[c].x);
    float S = 0.f;
#pragma unroll
    for (int c = 0; c < 8; ++c) {
      float w = expf(st[c].x - M);
      wch[tid][c] = w;
      S += w * st[c].y;
    }
    inv4[tid] = 1.f / (S * (1.f + 1e-8f));
  }
  __syncthreads();
  // 1. weighted reduce of chunk partials + load slots_prev
  for (int i = tid; i < 1024; i += 512) {
    int sl = i >> 8, d = i & 255;
    const float* pp = axp + ((size_t)n * 64 + sg + sl) * 256 + d;
    float a = 0.f;
#pragma unroll
    for (int c = 0; c < 8; ++c) a += wch[sl][c] * pp[(size_t)c * 2048];
    ax[sl][d] = a * inv4[sl];
    sp[sl][d] = slots_in[((size_t)n * 8 + sg + sl) * 256 + d];
  }
  __syncthreads();
  int e = tid & 255, h = tid >> 8;
  // 2. upd = ax @ WvT
  {
    float a0 = 0.f, a1 = 0.f;
    for (int d = 0; d < 256; ++d) {
      float w = WvT[d * 256 + e];
      a0 += ax[h * 2][d] * w;
      a1 += ax[h * 2 + 1][d] * w;
    }
    upd[h * 2][e] = a0;
    upd[h * 2 + 1][e] = a1;
  }
  __syncthreads();
  // 3. gi/gh
  for (int jj = tid; jj < 1536; jj += 512) {
    bool ihs = jj < 768;
    int j = ihs ? jj : jj - 768;
    const float* WT = ihs ? WihT : WhhT;
    const float* src = ihs ? &upd[0][0] : &sp[0][0];
    float a0 = 0.f, a1 = 0.f, a2 = 0.f, a3 = 0.f;
    for (int d = 0; d < 256; ++d) {
      float w = WT[(size_t)d * 768 + j];
      a0 += src[d] * w;
      a1 += src[256 + d] * w;
      a2 += src[512 + d] * w;
      a3 += src[768 + d] * w;
    }
    float bb = ihs ? b_ih[j] : b_hh[j];
    float* dst = ihs ? &gi[0][0] : &gh[0][0];
    dst[j] = a0 + bb;
    dst[768 + j] = a1 + bb;
    dst[1536 + j] = a2 + bb;
    dst[2304 + j] = a3 + bb;
  }
  __syncthreads();
  // 4. gates -> sn
  for (int i = tid; i < 1024; i += 512) {
    int sl = i >> 8, j = i & 255;
    float r = sigmf(gi[sl][j] + gh[sl][j]);
    float z = sigmf(gi[sl][j + 256] + gh[sl][j + 256]);
    float hh = tanhf(gi[sl][j + 512] + r * gh[sl][j + 512]);
    sn[sl][j] = (1.f - z) * hh + z * sp[sl][j];
  }
  __syncthreads();
  // 5. LN(sn) with lml params
  {
    int sl = tid >> 7, qq = tid & 127;
    float v0 = sn[sl][qq], v1 = sn[sl][qq + 128];
    float ps = wsum(v0 + v1);
    float pq = wsum(v0 * v0 + v1 * v1);
    int wid = tid >> 6;
    if ((tid & 63) == 0) { red[wid] = ps; red[8 + wid] = pq; }
    __syncthreads();
    float ssum = red[sl * 2] + red[sl * 2 + 1];
    float sqq  = red[8 + sl * 2] + red[8 + sl * 2 + 1];
    float mu = ssum * (1.f / 256.f);
    float var = sqq * (1.f / 256.f) - mu * mu;
    float rs = rsqrtf(var + 1e-5f);
    lnv[sl][qq]       = (v0 - mu) * rs * lml_g[qq] + lml_b[qq];
    lnv[sl][qq + 128] = (v1 - mu) * rs * lml_g[qq + 128] + lml_b[qq + 128];
  }
  __syncthreads();
  // 6. hid = relu(lnv @ W1T + b1)
  {
    float a0 = 0.f, a1 = 0.f;
    for (int d = 0; d < 256; ++d) {
      float w = W1T[d * 256 + e];
      a0 += lnv[h * 2][d] * w;
      a1 += lnv[h * 2 + 1][d] * w;
    }
    hid[h * 2][e]     = fmaxf(a0 + b1[e], 0.f);
    hid[h * 2 + 1][e] = fmaxf(a1 + b1[e], 0.f);
  }
  __syncthreads();
  // 7. out = sn + hid @ W2T + b2 (write + stash in ax as "snew")
  {
    float a0 = 0.f, a1 = 0.f;
    for (int d = 0; d < 256; ++d) {
      float w = W2T[d * 256 + e];
      a0 += hid[h * 2][d] * w;
      a1 += hid[h * 2 + 1][d] * w;
    }
    float o0 = sn[h * 2][e] + a0 + b2[e];
    float o1 = sn[h * 2 + 1][e] + a1 + b2[e];
    slots_out[((size_t)n * 8 + sg + h * 2) * 256 + e]     = o0;
    slots_out[((size_t)n * 8 + sg + h * 2 + 1) * 256 + e] = o1;
    ax[h * 2][e] = o0;
    ax[h * 2 + 1][e] = o1;
  }
  if (!doQw) return;
  __syncthreads();
  // 8. LN(snew) with lsl params -> sp
  {
    int sl = tid >> 7, qq = tid & 127;
    float v0 = ax[sl][qq], v1 = ax[sl][qq + 128];
    float ps = wsum(v0 + v1);
    float pq = wsum(v0 * v0 + v1 * v1);
    int wid = tid >> 6;
    if ((tid & 63) == 0) { red[wid] = ps; red[8 + wid] = pq; }
    __syncthreads();
    float ssum = red[sl * 2] + red[sl * 2 + 1];
    float sqq  = red[8 + sl * 2] + red[8 + sl * 2 + 1];
    float mu = ssum * (1.f / 256.f);
    float var = sqq * (1.f / 256.f) - mu * mu;
    float rs = rsqrtf(var + 1e-5f);
    sp[sl][qq]       = (v0 - mu) * rs * lsl_g[qq] + lsl_b[qq];
    sp[sl][qq + 128] = (v1 - mu) * rs * lsl_g[qq + 128] + lsl_b[qq + 128];
  }
  __syncthreads();
  // 9. qv = lnq @ WqT -> upd
  {
    float a0 = 0.f, a1 = 0.f;
    for (int d = 0; d < 256; ++d) {
      float w = WqT[d * 256 + e];
      a0 += sp[h * 2][d] * w;
      a1 += sp[h * 2 + 1][d] * w;
    }
    upd[h * 2][e] = a0;
    upd[h * 2 + 1][e] = a1;
  }
  __syncthreads();
  // 10. qw = qv @ Wk * scale -> hid
  {
    float c0 = 0.f, c1 = 0.f;
    for (int ee = 0; ee < 256; ++ee) {
      float w = Wk[(size_t)ee * 256 + e];
      c0 += upd[h * 2][ee] * w;
      c1 += upd[h * 2 + 1][ee] * w;
    }
    hid[h * 2][e]     = c0 * 0.0625f;
    hid[h * 2 + 1][e] = c1 * 0.0625f;
  }
  __syncthreads();
  // 11. pack bf16 qwb
  {
    int sl = tid >> 7, p = tid & 127;
    qwb[((size_t)n * 8 + sg + sl) * 128 + p] =
        (unsigned)f2bf(hid[sl][2 * p]) | ((unsigned)f2bf(hid[sl][2 * p + 1]) << 16);
  }
}

extern "C" void kernel_launch(void* const* d_in, const int* in_sizes, int n_in,
                              void* d_out, int out_size, void* d_ws, size_t ws_size,
                              hipStream_t stream) {
  (void)in_sizes; (void)n_in; (void)out_size; (void)ws_size;
  const float* inputs = (const float*)d_in[0];
  const float* noise  = (const float*)d_in[1];
  const float* smu    = (const float*)d_in[2];
  const float* slsig  = (const float*)d_in[3];
  const float* Wq     = (const float*)d_in[4];
  const float* Wk     = (const float*)d_in[5];
  const float* Wv     = (const float*)d_in[6];
  const float* W_ih   = (const float*)d_in[7];
  const float* W_hh   = (const float*)d_in[8];
  const float* b_ih   = (const float*)d_in[9];
  const float* b_hh   = (const float*)d_in[10];
  const float* W1     = (const float*)d_in[11];
  const float* b1     = (const float*)d_in[12];
  const float* W2     = (const float*)d_in[13];
  const float* b2     = (const float*)d_in[14];
  const float* lin_g  = (const float*)d_in[15];
  const float* lin_b  = (const float*)d_in[16];
  const float* lsl_g  = (const float*)d_in[17];
  const float* lsl_b  = (const float*)d_in[18];
  const float* lml_g  = (const float*)d_in[19];
  const float* lml_b  = (const float*)d_in[20];
  float* out = (float*)d_out;
  char* ws = (char*)d_ws;
  unsigned* x    = (unsigned*)(ws + 0);            // 134217728
  unsigned* xT   = (unsigned*)(ws + 134217728);    // 134217728
  unsigned* qwb  = (unsigned*)(ws + 268435456);    // 262144
  float2* stats  = (float2*)(ws + 268697600);      // 32768
  float* axp     = (float*)(ws + 268730368);       // 4194304
  float* WqT     = (float*)(ws + 272924672);       // 262144
  float* WvT     = (float*)(ws + 273186816);       // 262144
  float* WihT    = (float*)(ws + 273448960);       // 786432
  float* WhhT    = (float*)(ws + 274235392);       // 786432
  float* W1T     = (float*)(ws + 275021824);       // 262144
  float* W2T     = (float*)(ws + 275283968);       // 262144

  k_pre<<<dim3(66240), 256, 0, stream>>>(inputs, lin_g, lin_b, x,
                                         smu, slsig, noise, out,
                                         lsl_g, lsl_b, Wq, Wk, qwb,
                                         Wv, W_ih, W_hh, W1, W2,
                                         WqT, WvT, WihT, WhhT, W1T, W2T);
  k_trx<<<dim3(32, 2, BATCH), 256, 0, stream>>>(x, xT);
  for (int it = 0; it < 3; ++it) {
    k_att<<<dim3(8, BATCH), 256, 0, stream>>>(x, xT, qwb, stats, axp);
    k_update3<<<dim3(BATCH, 2), 512, 0, stream>>>(
        axp, stats, out, WvT, WihT, WhhT, b_ih, b_hh, W1T, b1, W2T, b2,
        lml_g, lml_b, lsl_g, lsl_b, WqT, Wk, qwb, (it < 2) ? 1 : 0, out);
  }
}

// Round 8
// 563.487 us; speedup vs baseline: 1.2211x; 1.2211x over previous
//
#include <hip/hip_runtime.h>
#include <math.h>

#define TOKENS 4096
#define BATCH 64

typedef __attribute__((ext_vector_type(8))) short bf16x8;
typedef __attribute__((ext_vector_type(4))) float f32x4;
union U4B { uint4 u; bf16x8 b; };

__device__ __forceinline__ float wsum(float v) {
#pragma unroll
  for (int m = 32; m >= 1; m >>= 1) v += __shfl_xor(v, m);
  return v;
}
__device__ __forceinline__ unsigned short f2bf(float f) {
  unsigned u = __float_as_uint(f);
  u += 0x7fffu + ((u >> 16) & 1u);
  return (unsigned short)(u >> 16);
}
__device__ __forceinline__ float sigmf(float x) { return 1.f / (1.f + expf(-x)); }

// ================= K_PRE: LN->x  |  weight transposes ==========
// grid 66176 x 256:
//   [0, 65536)     : LN(inputs) -> x bf16 (4 rows/block), coalesced
//   [65536, 66176) : 640 32x32 transpose tiles over the 6 weight matrices
__global__ __launch_bounds__(256) void k_pre(
    const float* __restrict__ in, const float* __restrict__ lin_g,
    const float* __restrict__ lin_b, unsigned* __restrict__ x,
    const float* __restrict__ Wq, const float* __restrict__ Wv,
    const float* __restrict__ Wih, const float* __restrict__ Whh,
    const float* __restrict__ W1, const float* __restrict__ W2,
    float* __restrict__ WqT, float* __restrict__ WvT, float* __restrict__ WihT,
    float* __restrict__ WhhT, float* __restrict__ W1T, float* __restrict__ W2T) {
  int bid = blockIdx.x, tid = threadIdx.x;
  if (bid < 65536) {
    int row = bid * 4 + (tid >> 6);
    int lane = tid & 63;
    const float* p = in + (size_t)row * 256 + lane * 4;
    float4 v = *(const float4*)p;
    float s  = wsum(v.x + v.y + v.z + v.w);
    float sq = wsum(v.x * v.x + v.y * v.y + v.z * v.z + v.w * v.w);
    float mu = s * (1.f / 256.f);
    float var = sq * (1.f / 256.f) - mu * mu;
    float rs = rsqrtf(var + 1e-5f);
    float4 gg = *(const float4*)(lin_g + lane * 4);
    float4 bb = *(const float4*)(lin_b + lane * 4);
    float y0 = (v.x - mu) * rs * gg.x + bb.x;
    float y1 = (v.y - mu) * rs * gg.y + bb.y;
    float y2 = (v.z - mu) * rs * gg.z + bb.z;
    float y3 = (v.w - mu) * rs * gg.w + bb.w;
    uint2 o;
    o.x = (unsigned)f2bf(y0) | ((unsigned)f2bf(y1) << 16);
    o.y = (unsigned)f2bf(y2) | ((unsigned)f2bf(y3) << 16);
    *(uint2*)(x + (size_t)row * 128 + lane * 2) = o;
    return;
  }
  {
    __shared__ float t[32][33];
    int t2 = bid - 65536;
    const float* S; float* D; int R; int tile;
    if (t2 < 64)       { S = Wq;  D = WqT;  R = 256; tile = t2; }
    else if (t2 < 128) { S = Wv;  D = WvT;  R = 256; tile = t2 - 64; }
    else if (t2 < 192) { S = W1;  D = W1T;  R = 256; tile = t2 - 128; }
    else if (t2 < 256) { S = W2;  D = W2T;  R = 256; tile = t2 - 192; }
    else if (t2 < 448) { S = Wih; D = WihT; R = 768; tile = t2 - 256; }
    else               { S = Whh; D = WhhT; R = 768; tile = t2 - 448; }
    int rt = R >> 5;
    int r0 = (tile % rt) * 32, c0 = (tile / rt) * 32;
    int ci = tid & 31, r8 = tid >> 5;
#pragma unroll
    for (int k = 0; k < 4; ++k) {
      int r = r8 + k * 8;
      t[r][ci] = S[(size_t)(r0 + r) * 256 + c0 + ci];
    }
    __syncthreads();
#pragma unroll
    for (int k = 0; k < 4; ++k) {
      int r = r8 + k * 8;
      D[(size_t)(c0 + r) * R + r0 + ci] = t[ci][r];
    }
  }
}

// ========== K_QW0: slot init + first-iteration qw (uses WqT) ==========
// grid (64, 8), 256 threads: one block per (n, slot)
__global__ __launch_bounds__(256) void k_qw0(
    const float* __restrict__ smu, const float* __restrict__ slsig,
    const float* __restrict__ noise, const float* __restrict__ lsl_g,
    const float* __restrict__ lsl_b, const float* __restrict__ WqT,
    const float* __restrict__ Wk, float* __restrict__ slots,
    unsigned* __restrict__ qwb) {
  __shared__ float ln[256];
  __shared__ float q[256];
  __shared__ float red[8];
  int n = blockIdx.x, s = blockIdx.y, tid = threadIdx.x;
  int sd = s * 256 + tid;
  float v = smu[sd] + expf(slsig[sd]) * noise[(size_t)n * 2048 + sd];
  slots[(size_t)n * 2048 + sd] = v;
  float ps = wsum(v), pq = wsum(v * v);
  if ((tid & 63) == 0) { red[tid >> 6] = ps; red[4 + (tid >> 6)] = pq; }
  __syncthreads();
  float sum = red[0] + red[1] + red[2] + red[3];
  float sqq = red[4] + red[5] + red[6] + red[7];
  float mu = sum * (1.f / 256.f);
  float var = sqq * (1.f / 256.f) - mu * mu;
  float rs = rsqrtf(var + 1e-5f);
  ln[tid] = (v - mu) * rs * lsl_g[tid] + lsl_b[tid];
  __syncthreads();
  float a = 0.f;
  for (int d = 0; d < 256; ++d) a += ln[d] * WqT[d * 256 + tid];
  q[tid] = a;
  __syncthreads();
  float c = 0.f;
  for (int e = 0; e < 256; ++e) c += q[e] * Wk[(size_t)e * 256 + tid];
  c *= 0.0625f;
  __syncthreads();
  ln[tid] = c;
  __syncthreads();
  if (tid < 128)
    qwb[((size_t)n * 8 + s) * 128 + tid] =
        (unsigned)f2bf(ln[2 * tid]) | ((unsigned)f2bf(ln[2 * tid + 1]) << 16);
}

// ========== K_TRX: bf16 transpose x[n][t][d] -> xT[n][d][t] ==================
// 128x128 tiles; read: 16 lanes cover one full 256B row segment (coalesced)
__global__ __launch_bounds__(256) void k_trx(const unsigned* __restrict__ x,
                                             unsigned* __restrict__ xT) {
  __shared__ unsigned u[128][65];
  int tt = blockIdx.x, dt = blockIdx.y, n = blockIdx.z;
  int tid = threadIdx.x;
  int t0 = tt * 128, c0 = dt * 64;
#pragma unroll
  for (int pass = 0; pass < 8; ++pass) {
    int row = pass * 16 + (tid >> 4);
    uint4 vv = *(const uint4*)(x + ((size_t)n * 4096 + t0 + row) * 128 + c0 + (tid & 15) * 4);
    unsigned* dr = &u[row][(tid & 15) * 4];
    dr[0] = vv.x; dr[1] = vv.y; dr[2] = vv.z; dr[3] = vv.w;
  }
  __syncthreads();
#pragma unroll
  for (int p = 0; p < 8; ++p) {
    int dl = p * 16 + (tid >> 4);
    int c = dl >> 1, hi = dl & 1;
    unsigned o[4];
#pragma unroll
    for (int k = 0; k < 4; ++k) {
      int j = (tid & 15) * 4 + k;
      unsigned u0 = u[2 * j][c], u1 = u[2 * j + 1][c];
      unsigned h0 = hi ? (u0 >> 16) : (u0 & 0xffffu);
      unsigned h1 = hi ? (u1 >> 16) : (u1 & 0xffffu);
      o[k] = h0 | (h1 << 16);
    }
    unsigned* dp = xT + ((size_t)n * 256 + dt * 128 + dl) * 2048 + tt * 64 + (tid & 15) * 4;
    *(uint4*)dp = *(uint4*)&o[0];
  }
}

// ========== K_ATT: QK^T (MFMA) + local softmax + PV (MFMA), per chunk ========
__global__ __launch_bounds__(256) void k_att(const unsigned* __restrict__ x,
                                             const unsigned* __restrict__ xT,
                                             const unsigned* __restrict__ qwb,
                                             float2* __restrict__ stats,
                                             float* __restrict__ axp) {
  __shared__ float ls[8][520];
  __shared__ unsigned at2[8][264];
  __shared__ float MS[8];
  int ch = blockIdx.x, n = blockIdx.y;
  int tid = threadIdx.x, wv = tid >> 6, l = tid & 63;
  int col = l & 15, g = l >> 4;
  uint4 a[8];
  {
    const unsigned* ap = qwb + ((size_t)n * 8 + (l & 7)) * 128 + g * 4;
#pragma unroll
    for (int kk = 0; kk < 8; ++kk) a[kk] = *(const uint4*)(ap + kk * 16);
  }
  // phase A: QK^T -> ls
  int tb = ch * 512 + wv * 128;
#pragma unroll
  for (int tt = 0; tt < 8; ++tt) {
    int t0 = tb + tt * 16;
    const unsigned* bp = x + ((size_t)n * 4096 + t0 + col) * 128 + g * 4;
    f32x4 acc = {0.f, 0.f, 0.f, 0.f};
#pragma unroll
    for (int kk = 0; kk < 8; ++kk) {
      U4B aa, bb;
      aa.u = a[kk];
      bb.u = *(const uint4*)(bp + kk * 16);
      acc = __builtin_amdgcn_mfma_f32_16x16x32_bf16(aa.b, bb.b, acc, 0, 0, 0);
    }
    if (g < 2) {
#pragma unroll
      for (int r = 0; r < 4; ++r) ls[g * 4 + r][wv * 128 + tt * 16 + col] = acc[r];
    }
  }
  __syncthreads();
  // phase B: local (M,S) per slot
  int s = tid >> 5, q = tid & 31;
  {
    float vv[16];
    float M = -3.4e38f;
#pragma unroll
    for (int j = 0; j < 16; ++j) {
      vv[j] = ls[s][q + j * 32];
      M = fmaxf(M, vv[j]);
    }
#pragma unroll
    for (int m = 16; m >= 1; m >>= 1) M = fmaxf(M, __shfl_xor(M, m));
    float S = 0.f;
#pragma unroll
    for (int j = 0; j < 16; ++j) S += expf(vv[j] - M);
#pragma unroll
    for (int m = 16; m >= 1; m >>= 1) S += __shfl_xor(S, m);
    if (q == 0) {
      stats[((size_t)n * 8 + s) * 8 + ch] = make_float2(M, S);
      MS[s] = M;
    }
  }
  __syncthreads();
  // phase C: at2 = packed bf16 exp(l - M_local)
  {
    float M = MS[s];
#pragma unroll
    for (int j = 0; j < 8; ++j) {
      int w = q + j * 32;
      float e0 = expf(ls[s][2 * w] - M);
      float e1 = expf(ls[s][2 * w + 1] - M);
      at2[s][w] = (unsigned)f2bf(e0) | ((unsigned)f2bf(e1) << 16);
    }
  }
  __syncthreads();
  // phase D: PV from LDS attn + global xT
  const unsigned* apl = &at2[l & 7][0];
#pragma unroll
  for (int dt = 0; dt < 4; ++dt) {
    int d0 = (wv * 4 + dt) * 16;
    const unsigned* bp = xT + ((size_t)n * 256 + d0 + col) * 2048 + ch * 256 + g * 4;
    f32x4 acc = {0.f, 0.f, 0.f, 0.f};
#pragma unroll
    for (int kk = 0; kk < 8; ++kk) {
      U4B aa, bb;
      aa.u = *(const uint4*)(apl + kk * 16 + g * 4);
      bb.u = *(const uint4*)(bp + kk * 16);
      acc = __builtin_amdgcn_mfma_f32_16x16x32_bf16(aa.b, bb.b, acc, 0, 0, 0);
    }
    if (g < 2) {
#pragma unroll
      for (int r = 0; r < 4; ++r)
        axp[(((size_t)n * 8 + ch) * 8 + g * 4 + r) * 256 + d0 + col] = acc[r];
    }
  }
}

// ========== K_UPDATE3: combine chunks, Wv, GRU, LN, MLP (+ next-iter qw) =====
__global__ __launch_bounds__(512) void k_update3(
    const float* __restrict__ axp, const float2* __restrict__ stats,
    const float* __restrict__ slots_in,
    const float* __restrict__ WvT, const float* __restrict__ WihT,
    const float* __restrict__ WhhT, const float* __restrict__ b_ih,
    const float* __restrict__ b_hh, const float* __restrict__ W1T,
    const float* __restrict__ b1, const float* __restrict__ W2T,
    const float* __restrict__ b2, const float* __restrict__ lml_g,
    const float* __restrict__ lml_b, const float* __restrict__ lsl_g,
    const float* __restrict__ lsl_b, const float* __restrict__ WqT,
    const float* __restrict__ Wk, unsigned* __restrict__ qwb, int doQw,
    float* __restrict__ slots_out) {
  __shared__ float ax[4][256];
  __shared__ float sp[4][256];
  __shared__ float upd[4][256];
  __shared__ float gi[4][768];
  __shared__ float gh[4][768];
  __shared__ float sn[4][256];
  __shared__ float lnv[4][256];
  __shared__ float hid[4][256];
  __shared__ float red[16];
  __shared__ float wch[4][8];
  __shared__ float inv4[4];
  int n = blockIdx.x, sg = blockIdx.y * 4;
  int tid = threadIdx.x;
  if (tid < 4) {
    const float2* st = stats + ((size_t)n * 8 + sg + tid) * 8;
    float M = -3.4e38f;
#pragma unroll
    for (int c = 0; c < 8; ++c) M = fmaxf(M, st[c].x);
    float S = 0.f;
#pragma unroll
    for (int c = 0; c < 8; ++c) {
      float w = expf(st[c].x - M);
      wch[tid][c] = w;
      S += w * st[c].y;
    }
    inv4[tid] = 1.f / (S * (1.f + 1e-8f));
  }
  __syncthreads();
  for (int i = tid; i < 1024; i += 512) {
    int sl = i >> 8, d = i & 255;
    const float* pp = axp + ((size_t)n * 64 + sg + sl) * 256 + d;
    float a = 0.f;
#pragma unroll
    for (int c = 0; c < 8; ++c) a += wch[sl][c] * pp[(size_t)c * 2048];
    ax[sl][d] = a * inv4[sl];
    sp[sl][d] = slots_in[((size_t)n * 8 + sg + sl) * 256 + d];
  }
  __syncthreads();
  int e = tid & 255, h = tid >> 8;
  {
    float a0 = 0.f, a1 = 0.f;
    for (int d = 0; d < 256; ++d) {
      float w = WvT[d * 256 + e];
      a0 += ax[h * 2][d] * w;
      a1 += ax[h * 2 + 1][d] * w;
    }
    upd[h * 2][e] = a0;
    upd[h * 2 + 1][e] = a1;
  }
  __syncthreads();
  for (int jj = tid; jj < 1536; jj += 512) {
    bool ihs = jj < 768;
    int j = ihs ? jj : jj - 768;
    const float* WT = ihs ? WihT : WhhT;
    const float* src = ihs ? &upd[0][0] : &sp[0][0];
    float a0 = 0.f, a1 = 0.f, a2 = 0.f, a3 = 0.f;
    for (int d = 0; d < 256; ++d) {
      float w = WT[(size_t)d * 768 + j];
      a0 += src[d] * w;
      a1 += src[256 + d] * w;
      a2 += src[512 + d] * w;
      a3 += src[768 + d] * w;
    }
    float bb = ihs ? b_ih[j] : b_hh[j];
    float* dst = ihs ? &gi[0][0] : &gh[0][0];
    dst[j] = a0 + bb;
    dst[768 + j] = a1 + bb;
    dst[1536 + j] = a2 + bb;
    dst[2304 + j] = a3 + bb;
  }
  __syncthreads();
  for (int i = tid; i < 1024; i += 512) {
    int sl = i >> 8, j = i & 255;
    float r = sigmf(gi[sl][j] + gh[sl][j]);
    float z = sigmf(gi[sl][j + 256] + gh[sl][j + 256]);
    float hh = tanhf(gi[sl][j + 512] + r * gh[sl][j + 512]);
    sn[sl][j] = (1.f - z) * hh + z * sp[sl][j];
  }
  __syncthreads();
  {
    int sl = tid >> 7, qq = tid & 127;
    float v0 = sn[sl][qq], v1 = sn[sl][qq + 128];
    float ps = wsum(v0 + v1);
    float pq = wsum(v0 * v0 + v1 * v1);
    int wid = tid >> 6;
    if ((tid & 63) == 0) { red[wid] = ps; red[8 + wid] = pq; }
    __syncthreads();
    float ssum = red[sl * 2] + red[sl * 2 + 1];
    float sqq  = red[8 + sl * 2] + red[8 + sl * 2 + 1];
    float mu = ssum * (1.f / 256.f);
    float var = sqq * (1.f / 256.f) - mu * mu;
    float rs = rsqrtf(var + 1e-5f);
    lnv[sl][qq]       = (v0 - mu) * rs * lml_g[qq] + lml_b[qq];
    lnv[sl][qq + 128] = (v1 - mu) * rs * lml_g[qq + 128] + lml_b[qq + 128];
  }
  __syncthreads();
  {
    float a0 = 0.f, a1 = 0.f;
    for (int d = 0; d < 256; ++d) {
      float w = W1T[d * 256 + e];
      a0 += lnv[h * 2][d] * w;
      a1 += lnv[h * 2 + 1][d] * w;
    }
    hid[h * 2][e]     = fmaxf(a0 + b1[e], 0.f);
    hid[h * 2 + 1][e] = fmaxf(a1 + b1[e], 0.f);
  }
  __syncthreads();
  {
    float a0 = 0.f, a1 = 0.f;
    for (int d = 0; d < 256; ++d) {
      float w = W2T[d * 256 + e];
      a0 += hid[h * 2][d] * w;
      a1 += hid[h * 2 + 1][d] * w;
    }
    float o0 = sn[h * 2][e] + a0 + b2[e];
    float o1 = sn[h * 2 + 1][e] + a1 + b2[e];
    slots_out[((size_t)n * 8 + sg + h * 2) * 256 + e]     = o0;
    slots_out[((size_t)n * 8 + sg + h * 2 + 1) * 256 + e] = o1;
    ax[h * 2][e] = o0;
    ax[h * 2 + 1][e] = o1;
  }
  if (!doQw) return;
  __syncthreads();
  {
    int sl = tid >> 7, qq = tid & 127;
    float v0 = ax[sl][qq], v1 = ax[sl][qq + 128];
    float ps = wsum(v0 + v1);
    float pq = wsum(v0 * v0 + v1 * v1);
    int wid = tid >> 6;
    if ((tid & 63) == 0) { red[wid] = ps; red[8 + wid] = pq; }
    __syncthreads();
    float ssum = red[sl * 2] + red[sl * 2 + 1];
    float sqq  = red[8 + sl * 2] + red[8 + sl * 2 + 1];
    float mu = ssum * (1.f / 256.f);
    float var = sqq * (1.f / 256.f) - mu * mu;
    float rs = rsqrtf(var + 1e-5f);
    sp[sl][qq]       = (v0 - mu) * rs * lsl_g[qq] + lsl_b[qq];
    sp[sl][qq + 128] = (v1 - mu) * rs * lsl_g[qq + 128] + lsl_b[qq + 128];
  }
  __syncthreads();
  {
    float a0 = 0.f, a1 = 0.f;
    for (int d = 0; d < 256; ++d) {
      float w = WqT[d * 256 + e];
      a0 += sp[h * 2][d] * w;
      a1 += sp[h * 2 + 1][d] * w;
    }
    upd[h * 2][e] = a0;
    upd[h * 2 + 1][e] = a1;
  }
  __syncthreads();
  {
    float c0 = 0.f, c1 = 0.f;
    for (int ee = 0; ee < 256; ++ee) {
      float w = Wk[(size_t)ee * 256 + e];
      c0 += upd[h * 2][ee] * w;
      c1 += upd[h * 2 + 1][ee] * w;
    }
    hid[h * 2][e]     = c0 * 0.0625f;
    hid[h * 2 + 1][e] = c1 * 0.0625f;
  }
  __syncthreads();
  {
    int sl = tid >> 7, p = tid & 127;
    qwb[((size_t)n * 8 + sg + sl) * 128 + p] =
        (unsigned)f2bf(hid[sl][2 * p]) | ((unsigned)f2bf(hid[sl][2 * p + 1]) << 16);
  }
}

extern "C" void kernel_launch(void* const* d_in, const int* in_sizes, int n_in,
                              void* d_out, int out_size, void* d_ws, size_t ws_size,
                              hipStream_t stream) {
  (void)in_sizes; (void)n_in; (void)out_size; (void)ws_size;
  const float* inputs = (const float*)d_in[0];
  const float* noise  = (const float*)d_in[1];
  const float* smu    = (const float*)d_in[2];
  const float* slsig  = (const float*)d_in[3];
  const float* Wq     = (const float*)d_in[4];
  const float* Wk     = (const float*)d_in[5];
  const float* Wv     = (const float*)d_in[6];
  const float* W_ih   = (const float*)d_in[7];
  const float* W_hh   = (const float*)d_in[8];
  const float* b_ih   = (const float*)d_in[9];
  const float* b_hh   = (const float*)d_in[10];
  const float* W1     = (const float*)d_in[11];
  const float* b1     = (const float*)d_in[12];
  const float* W2     = (const float*)d_in[13];
  const float* b2     = (const float*)d_in[14];
  const float* lin_g  = (const float*)d_in[15];
  const float* lin_b  = (const float*)d_in[16];
  const float* lsl_g  = (const float*)d_in[17];
  const float* lsl_b  = (const float*)d_in[18];
  const float* lml_g  = (const float*)d_in[19];
  const float* lml_b  = (const float*)d_in[20];
  float* out = (float*)d_out;
  char* ws = (char*)d_ws;
  unsigned* x    = (unsigned*)(ws + 0);            // 134217728
  unsigned* xT   = (unsigned*)(ws + 134217728);    // 134217728
  unsigned* qwb  = (unsigned*)(ws + 268435456);    // 262144
  float2* stats  = (float2*)(ws + 268697600);      // 32768
  float* axp     = (float*)(ws + 268730368);       // 4194304
  float* WqT     = (float*)(ws + 272924672);       // 262144
  float* WvT     = (float*)(ws + 273186816);       // 262144
  float* WihT    = (float*)(ws + 273448960);       // 786432
  float* WhhT    = (float*)(ws + 274235392);       // 786432
  float* W1T     = (float*)(ws + 275021824);       // 262144
  float* W2T     = (float*)(ws + 275283968);       // 262144

  k_pre<<<dim3(66176), 256, 0, stream>>>(inputs, lin_g, lin_b, x,
                                         Wq, Wv, W_ih, W_hh, W1, W2,
                                         WqT, WvT, WihT, WhhT, W1T, W2T);
  k_trx<<<dim3(32, 2, BATCH), 256, 0, stream>>>(x, xT);
  k_qw0<<<dim3(BATCH, 8), 256, 0, stream>>>(smu, slsig, noise, lsl_g, lsl_b,
                                            WqT, Wk, out, qwb);
  for (int it = 0; it < 3; ++it) {
    k_att<<<dim3(8, BATCH), 256, 0, stream>>>(x, xT, qwb, stats, axp);
    k_update3<<<dim3(BATCH, 2), 512, 0, stream>>>(
        axp, stats, out, WvT, WihT, WhhT, b_ih, b_hh, W1T, b1, W2T, b2,
        lml_g, lml_b, lsl_g, lsl_b, WqT, Wk, qwb, (it < 2) ? 1 : 0, out);
  }
}

// Round 9
// 463.468 us; speedup vs baseline: 1.4846x; 1.2158x over previous
//
#include <hip/hip_runtime.h>
#include <math.h>

#define TOKENS 4096
#define BATCH 64

typedef __attribute__((ext_vector_type(8))) short bf16x8;
typedef __attribute__((ext_vector_type(4))) float f32x4;
union U4B { uint4 u; bf16x8 b; };
union U2x2B { uint2 u[2]; bf16x8 b; };

__device__ __forceinline__ float wsum(float v) {
#pragma unroll
  for (int m = 32; m >= 1; m >>= 1) v += __shfl_xor(v, m);
  return v;
}
__device__ __forceinline__ unsigned short f2bf(float f) {
  unsigned u = __float_as_uint(f);
  u += 0x7fffu + ((u >> 16) & 1u);
  return (unsigned short)(u >> 16);
}
__device__ __forceinline__ float bflo(unsigned p) { return __uint_as_float(p << 16); }
__device__ __forceinline__ float bfhi(unsigned p) { return __uint_as_float(p & 0xffff0000u); }
__device__ __forceinline__ float sigmf(float x) { return 1.f / (1.f + expf(-x)); }

// ================= K_PRE: LN->x  |  weight transposes ==========
__global__ __launch_bounds__(256) void k_pre(
    const float* __restrict__ in, const float* __restrict__ lin_g,
    const float* __restrict__ lin_b, unsigned* __restrict__ x,
    const float* __restrict__ Wq, const float* __restrict__ Wv,
    const float* __restrict__ Wih, const float* __restrict__ Whh,
    const float* __restrict__ W1, const float* __restrict__ W2,
    float* __restrict__ WqT, float* __restrict__ WvT, float* __restrict__ WihT,
    float* __restrict__ WhhT, float* __restrict__ W1T, float* __restrict__ W2T) {
  int bid = blockIdx.x, tid = threadIdx.x;
  if (bid < 65536) {
    int row = bid * 4 + (tid >> 6);
    int lane = tid & 63;
    const float* p = in + (size_t)row * 256 + lane * 4;
    float4 v = *(const float4*)p;
    float s  = wsum(v.x + v.y + v.z + v.w);
    float sq = wsum(v.x * v.x + v.y * v.y + v.z * v.z + v.w * v.w);
    float mu = s * (1.f / 256.f);
    float var = sq * (1.f / 256.f) - mu * mu;
    float rs = rsqrtf(var + 1e-5f);
    float4 gg = *(const float4*)(lin_g + lane * 4);
    float4 bb = *(const float4*)(lin_b + lane * 4);
    float y0 = (v.x - mu) * rs * gg.x + bb.x;
    float y1 = (v.y - mu) * rs * gg.y + bb.y;
    float y2 = (v.z - mu) * rs * gg.z + bb.z;
    float y3 = (v.w - mu) * rs * gg.w + bb.w;
    uint2 o;
    o.x = (unsigned)f2bf(y0) | ((unsigned)f2bf(y1) << 16);
    o.y = (unsigned)f2bf(y2) | ((unsigned)f2bf(y3) << 16);
    *(uint2*)(x + (size_t)row * 128 + lane * 2) = o;
    return;
  }
  {
    __shared__ float t[32][33];
    int t2 = bid - 65536;
    const float* S; float* D; int R; int tile;
    if (t2 < 64)       { S = Wq;  D = WqT;  R = 256; tile = t2; }
    else if (t2 < 128) { S = Wv;  D = WvT;  R = 256; tile = t2 - 64; }
    else if (t2 < 192) { S = W1;  D = W1T;  R = 256; tile = t2 - 128; }
    else if (t2 < 256) { S = W2;  D = W2T;  R = 256; tile = t2 - 192; }
    else if (t2 < 448) { S = Wih; D = WihT; R = 768; tile = t2 - 256; }
    else               { S = Whh; D = WhhT; R = 768; tile = t2 - 448; }
    int rt = R >> 5;
    int r0 = (tile % rt) * 32, c0 = (tile / rt) * 32;
    int ci = tid & 31, r8 = tid >> 5;
#pragma unroll
    for (int k = 0; k < 4; ++k) {
      int r = r8 + k * 8;
      t[r][ci] = S[(size_t)(r0 + r) * 256 + c0 + ci];
    }
    __syncthreads();
#pragma unroll
    for (int k = 0; k < 4; ++k) {
      int r = r8 + k * 8;
      D[(size_t)(c0 + r) * R + r0 + ci] = t[ci][r];
    }
  }
}

// ========== K_QW0: slot init + first-iteration qw (uses WqT) ==========
__global__ __launch_bounds__(256) void k_qw0(
    const float* __restrict__ smu, const float* __restrict__ slsig,
    const float* __restrict__ noise, const float* __restrict__ lsl_g,
    const float* __restrict__ lsl_b, const float* __restrict__ WqT,
    const float* __restrict__ Wk, float* __restrict__ slots,
    unsigned* __restrict__ qwb) {
  __shared__ float ln[256];
  __shared__ float q[256];
  __shared__ float red[8];
  int n = blockIdx.x, s = blockIdx.y, tid = threadIdx.x;
  int sd = s * 256 + tid;
  float v = smu[sd] + expf(slsig[sd]) * noise[(size_t)n * 2048 + sd];
  slots[(size_t)n * 2048 + sd] = v;
  float ps = wsum(v), pq = wsum(v * v);
  if ((tid & 63) == 0) { red[tid >> 6] = ps; red[4 + (tid >> 6)] = pq; }
  __syncthreads();
  float sum = red[0] + red[1] + red[2] + red[3];
  float sqq = red[4] + red[5] + red[6] + red[7];
  float mu = sum * (1.f / 256.f);
  float var = sqq * (1.f / 256.f) - mu * mu;
  float rs = rsqrtf(var + 1e-5f);
  ln[tid] = (v - mu) * rs * lsl_g[tid] + lsl_b[tid];
  __syncthreads();
  float a = 0.f;
  for (int d = 0; d < 256; ++d) a += ln[d] * WqT[d * 256 + tid];
  q[tid] = a;
  __syncthreads();
  float c = 0.f;
  for (int e = 0; e < 256; ++e) c += q[e] * Wk[(size_t)e * 256 + tid];
  c *= 0.0625f;
  __syncthreads();
  ln[tid] = c;
  __syncthreads();
  if (tid < 128)
    qwb[((size_t)n * 8 + s) * 128 + tid] =
        (unsigned)f2bf(ln[2 * tid]) | ((unsigned)f2bf(ln[2 * tid + 1]) << 16);
}

// ========== K_ATT: stage x chunk in LDS; QK^T (MFMA) + softmax + PV (VALU) ===
// grid (64 chunks of 64 tokens, 64 n), 256 threads = 4 waves.
// outputs: stats[n][s][64] = (M_local, S_local); axp[n][ch][s][d] unnormalized
__global__ __launch_bounds__(256) void k_att(const unsigned* __restrict__ x,
                                             const unsigned* __restrict__ qwb,
                                             float2* __restrict__ stats,
                                             float* __restrict__ axp) {
  __shared__ unsigned xs[64][130];   // [t_local][d-pair], pad 130 for banks
  __shared__ float lsT[64][8];       // [t_local][slot] logits -> exp values
  __shared__ float redM[8][4], redS[8][4];
  int ch = blockIdx.x, n = blockIdx.y;
  int tid = threadIdx.x, wv = tid >> 6, l = tid & 63;
  int col = l & 15, g = l >> 4;
  // phase A0: cooperative load of x chunk (64 rows x 512B), coalesced
  {
    int lane32 = tid & 31, g8 = tid >> 5;
    const unsigned* src = x + ((size_t)n * 4096 + ch * 64) * 128 + lane32 * 4;
#pragma unroll
    for (int p = 0; p < 8; ++p) {
      int row = p * 8 + g8;
      uint4 vv = *(const uint4*)(src + (size_t)row * 128);
      unsigned* dr = &xs[row][lane32 * 4];
      *(uint2*)dr = make_uint2(vv.x, vv.y);
      *(uint2*)(dr + 2) = make_uint2(vv.z, vv.w);
    }
  }
  // A-fragments (qw) from global, 8 x uint4 per lane
  uint4 a[8];
  {
    const unsigned* ap = qwb + ((size_t)n * 8 + (l & 7)) * 128 + g * 4;
#pragma unroll
    for (int kk = 0; kk < 8; ++kk) a[kk] = *(const uint4*)(ap + kk * 16);
  }
  __syncthreads();
  // phase A: QK^T via MFMA; wave wv covers tokens [wv*16, wv*16+16)
  {
    int t0 = wv * 16;
    const unsigned* xr = &xs[t0 + col][0];
    f32x4 acc = {0.f, 0.f, 0.f, 0.f};
#pragma unroll
    for (int kk = 0; kk < 8; ++kk) {
      U4B aa;
      aa.u = a[kk];
      U2x2B bb;
      bb.u[0] = *(const uint2*)(xr + kk * 16 + g * 4);
      bb.u[1] = *(const uint2*)(xr + kk * 16 + g * 4 + 2);
      acc = __builtin_amdgcn_mfma_f32_16x16x32_bf16(aa.b, bb.b, acc, 0, 0, 0);
    }
    if (g < 2) {
#pragma unroll
      for (int r = 0; r < 4; ++r) lsT[t0 + col][g * 4 + r] = acc[r];
    }
  }
  __syncthreads();
  // phase B: per-slot local max over 64 tokens
  int s = tid & 7, tg = tid >> 3;  // tg 0..31
  float l0 = lsT[tg][s], l1 = lsT[tg + 32][s];
  {
    float M = fmaxf(l0, l1);
    M = fmaxf(M, __shfl_xor(M, 8));
    M = fmaxf(M, __shfl_xor(M, 16));
    M = fmaxf(M, __shfl_xor(M, 32));
    if ((tid & 63) < 8) redM[s][tid >> 6] = M;
  }
  __syncthreads();
  float Mf = fmaxf(fmaxf(redM[s][0], redM[s][1]), fmaxf(redM[s][2], redM[s][3]));
  // phase C: exp in place + local sum
  {
    float e0 = expf(l0 - Mf), e1 = expf(l1 - Mf);
    lsT[tg][s] = e0;
    lsT[tg + 32][s] = e1;
    float S = e0 + e1;
    S += __shfl_xor(S, 8);
    S += __shfl_xor(S, 16);
    S += __shfl_xor(S, 32);
    if ((tid & 63) < 8) redS[s][tid >> 6] = S;
  }
  __syncthreads();
  if (tid < 8) {
    float M = fmaxf(fmaxf(redM[tid][0], redM[tid][1]), fmaxf(redM[tid][2], redM[tid][3]));
    float S = redS[tid][0] + redS[tid][1] + redS[tid][2] + redS[tid][3];
    stats[((size_t)n * 8 + tid) * 64 + ch] = make_float2(M, S);
  }
  // phase D: PV on VALU; thread owns column d = tid
  {
    int d = tid;
    float acc[8] = {0, 0, 0, 0, 0, 0, 0, 0};
#pragma unroll 8
    for (int t = 0; t < 64; ++t) {
      unsigned pw = xs[t][d >> 1];
      float xv = (d & 1) ? bfhi(pw) : bflo(pw);
      float4 a0 = *(const float4*)&lsT[t][0];
      float4 a1 = *(const float4*)&lsT[t][4];
      acc[0] += a0.x * xv; acc[1] += a0.y * xv;
      acc[2] += a0.z * xv; acc[3] += a0.w * xv;
      acc[4] += a1.x * xv; acc[5] += a1.y * xv;
      acc[6] += a1.z * xv; acc[7] += a1.w * xv;
    }
    float* op = axp + (((size_t)n * 64 + ch) * 8) * 256 + d;
#pragma unroll
    for (int ss = 0; ss < 8; ++ss) op[ss * 256] = acc[ss];
  }
}

// ========== K_UPDATE3: combine chunks, Wv, GRU, LN, MLP (+ next-iter qw) =====
__global__ __launch_bounds__(512) void k_update3(
    const float* __restrict__ axp, const float2* __restrict__ stats,
    const float* __restrict__ slots_in,
    const float* __restrict__ WvT, const float* __restrict__ WihT,
    const float* __restrict__ WhhT, const float* __restrict__ b_ih,
    const float* __restrict__ b_hh, const float* __restrict__ W1T,
    const float* __restrict__ b1, const float* __restrict__ W2T,
    const float* __restrict__ b2, const float* __restrict__ lml_g,
    const float* __restrict__ lml_b, const float* __restrict__ lsl_g,
    const float* __restrict__ lsl_b, const float* __restrict__ WqT,
    const float* __restrict__ Wk, unsigned* __restrict__ qwb, int doQw,
    float* __restrict__ slots_out) {
  __shared__ float ax[4][256];
  __shared__ float sp[4][256];
  __shared__ float upd[4][256];
  __shared__ float gi[4][768];
  __shared__ float gh[4][768];
  __shared__ float sn[4][256];
  __shared__ float lnv[4][256];
  __shared__ float hid[4][256];
  __shared__ float red[16];
  __shared__ float wch[4][64];
  __shared__ float inv4[4];
  int n = blockIdx.x, sg = blockIdx.y * 4;
  int tid = threadIdx.x;
  if (tid < 4) {
    const float2* st = stats + ((size_t)n * 8 + sg + tid) * 64;
    float M = -3.4e38f;
#pragma unroll
    for (int c = 0; c < 64; ++c) M = fmaxf(M, st[c].x);
    float S = 0.f;
#pragma unroll
    for (int c = 0; c < 64; ++c) {
      float w = expf(st[c].x - M);
      wch[tid][c] = w;
      S += w * st[c].y;
    }
    inv4[tid] = 1.f / (S * (1.f + 1e-8f));
  }
  __syncthreads();
  for (int i = tid; i < 1024; i += 512) {
    int sl = i >> 8, d = i & 255;
    const float* pp = axp + ((size_t)n * 512 + sg + sl) * 256 + d;
    float a = 0.f;
#pragma unroll
    for (int c = 0; c < 64; ++c) a += wch[sl][c] * pp[(size_t)c * 2048];
    ax[sl][d] = a * inv4[sl];
    sp[sl][d] = slots_in[((size_t)n * 8 + sg + sl) * 256 + d];
  }
  __syncthreads();
  int e = tid & 255, h = tid >> 8;
  {
    float a0 = 0.f, a1 = 0.f;
    for (int d = 0; d < 256; ++d) {
      float w = WvT[d * 256 + e];
      a0 += ax[h * 2][d] * w;
      a1 += ax[h * 2 + 1][d] * w;
    }
    upd[h * 2][e] = a0;
    upd[h * 2 + 1][e] = a1;
  }
  __syncthreads();
  for (int jj = tid; jj < 1536; jj += 512) {
    bool ihs = jj < 768;
    int j = ihs ? jj : jj - 768;
    const float* WT = ihs ? WihT : WhhT;
    const float* src = ihs ? &upd[0][0] : &sp[0][0];
    float a0 = 0.f, a1 = 0.f, a2 = 0.f, a3 = 0.f;
    for (int d = 0; d < 256; ++d) {
      float w = WT[(size_t)d * 768 + j];
      a0 += src[d] * w;
      a1 += src[256 + d] * w;
      a2 += src[512 + d] * w;
      a3 += src[768 + d] * w;
    }
    float bb = ihs ? b_ih[j] : b_hh[j];
    float* dst = ihs ? &gi[0][0] : &gh[0][0];
    dst[j] = a0 + bb;
    dst[768 + j] = a1 + bb;
    dst[1536 + j] = a2 + bb;
    dst[2304 + j] = a3 + bb;
  }
  __syncthreads();
  for (int i = tid; i < 1024; i += 512) {
    int sl = i >> 8, j = i & 255;
    float r = sigmf(gi[sl][j] + gh[sl][j]);
    float z = sigmf(gi[sl][j + 256] + gh[sl][j + 256]);
    float hh = tanhf(gi[sl][j + 512] + r * gh[sl][j + 512]);
    sn[sl][j] = (1.f - z) * hh + z * sp[sl][j];
  }
  __syncthreads();
  {
    int sl = tid >> 7, qq = tid & 127;
    float v0 = sn[sl][qq], v1 = sn[sl][qq + 128];
    float ps = wsum(v0 + v1);
    float pq = wsum(v0 * v0 + v1 * v1);
    int wid = tid >> 6;
    if ((tid & 63) == 0) { red[wid] = ps; red[8 + wid] = pq; }
    __syncthreads();
    float ssum = red[sl * 2] + red[sl * 2 + 1];
    float sqq  = red[8 + sl * 2] + red[8 + sl * 2 + 1];
    float mu = ssum * (1.f / 256.f);
    float var = sqq * (1.f / 256.f) - mu * mu;
    float rs = rsqrtf(var + 1e-5f);
    lnv[sl][qq]       = (v0 - mu) * rs * lml_g[qq] + lml_b[qq];
    lnv[sl][qq + 128] = (v1 - mu) * rs * lml_g[qq + 128] + lml_b[qq + 128];
  }
  __syncthreads();
  {
    float a0 = 0.f, a1 = 0.f;
    for (int d = 0; d < 256; ++d) {
      float w = W1T[d * 256 + e];
      a0 += lnv[h * 2][d] * w;
      a1 += lnv[h * 2 + 1][d] * w;
    }
    hid[h * 2][e]     = fmaxf(a0 + b1[e], 0.f);
    hid[h * 2 + 1][e] = fmaxf(a1 + b1[e], 0.f);
  }
  __syncthreads();
  {
    float a0 = 0.f, a1 = 0.f;
    for (int d = 0; d < 256; ++d) {
      float w = W2T[d * 256 + e];
      a0 += hid[h * 2][d] * w;
      a1 += hid[h * 2 + 1][d] * w;
    }
    float o0 = sn[h * 2][e] + a0 + b2[e];
    float o1 = sn[h * 2 + 1][e] + a1 + b2[e];
    slots_out[((size_t)n * 8 + sg + h * 2) * 256 + e]     = o0;
    slots_out[((size_t)n * 8 + sg + h * 2 + 1) * 256 + e] = o1;
    ax[h * 2][e] = o0;
    ax[h * 2 + 1][e] = o1;
  }
  if (!doQw) return;
  __syncthreads();
  {
    int sl = tid >> 7, qq = tid & 127;
    float v0 = ax[sl][qq], v1 = ax[sl][qq + 128];
    float ps = wsum(v0 + v1);
    float pq = wsum(v0 * v0 + v1 * v1);
    int wid = tid >> 6;
    if ((tid & 63) == 0) { red[wid] = ps; red[8 + wid] = pq; }
    __syncthreads();
    float ssum = red[sl * 2] + red[sl * 2 + 1];
    float sqq  = red[8 + sl * 2] + red[8 + sl * 2 + 1];
    float mu = ssum * (1.f / 256.f);
    float var = sqq * (1.f / 256.f) - mu * mu;
    float rs = rsqrtf(var + 1e-5f);
    sp[sl][qq]       = (v0 - mu) * rs * lsl_g[qq] + lsl_b[qq];
    sp[sl][qq + 128] = (v1 - mu) * rs * lsl_g[qq + 128] + lsl_b[qq + 128];
  }
  __syncthreads();
  {
    float a0 = 0.f, a1 = 0.f;
    for (int d = 0; d < 256; ++d) {
      float w = WqT[d * 256 + e];
      a0 += sp[h * 2][d] * w;
      a1 += sp[h * 2 + 1][d] * w;
    }
    upd[h * 2][e] = a0;
    upd[h * 2 + 1][e] = a1;
  }
  __syncthreads();
  {
    float c0 = 0.f, c1 = 0.f;
    for (int ee = 0; ee < 256; ++ee) {
      float w = Wk[(size_t)ee * 256 + e];
      c0 += upd[h * 2][ee] * w;
      c1 += upd[h * 2 + 1][ee] * w;
    }
    hid[h * 2][e]     = c0 * 0.0625f;
    hid[h * 2 + 1][e] = c1 * 0.0625f;
  }
  __syncthreads();
  {
    int sl = tid >> 7, p = tid & 127;
    qwb[((size_t)n * 8 + sg + sl) * 128 + p] =
        (unsigned)f2bf(hid[sl][2 * p]) | ((unsigned)f2bf(hid[sl][2 * p + 1]) << 16);
  }
}

extern "C" void kernel_launch(void* const* d_in, const int* in_sizes, int n_in,
                              void* d_out, int out_size, void* d_ws, size_t ws_size,
                              hipStream_t stream) {
  (void)in_sizes; (void)n_in; (void)out_size; (void)ws_size;
  const float* inputs = (const float*)d_in[0];
  const float* noise  = (const float*)d_in[1];
  const float* smu    = (const float*)d_in[2];
  const float* slsig  = (const float*)d_in[3];
  const float* Wq     = (const float*)d_in[4];
  const float* Wk     = (const float*)d_in[5];
  const float* Wv     = (const float*)d_in[6];
  const float* W_ih   = (const float*)d_in[7];
  const float* W_hh   = (const float*)d_in[8];
  const float* b_ih   = (const float*)d_in[9];
  const float* b_hh   = (const float*)d_in[10];
  const float* W1     = (const float*)d_in[11];
  const float* b1     = (const float*)d_in[12];
  const float* W2     = (const float*)d_in[13];
  const float* b2     = (const float*)d_in[14];
  const float* lin_g  = (const float*)d_in[15];
  const float* lin_b  = (const float*)d_in[16];
  const float* lsl_g  = (const float*)d_in[17];
  const float* lsl_b  = (const float*)d_in[18];
  const float* lml_g  = (const float*)d_in[19];
  const float* lml_b  = (const float*)d_in[20];
  float* out = (float*)d_out;
  char* ws = (char*)d_ws;
  unsigned* x    = (unsigned*)(ws + 0);            // 134217728
  unsigned* qwb  = (unsigned*)(ws + 134217728);    // 262144
  float2* stats  = (float2*)(ws + 134479872);      // 262144
  float* axp     = (float*)(ws + 134742016);       // 33554432
  float* WqT     = (float*)(ws + 168296448);       // 262144
  float* WvT     = (float*)(ws + 168558592);       // 262144
  float* WihT    = (float*)(ws + 168820736);       // 786432
  float* WhhT    = (float*)(ws + 169607168);       // 786432
  float* W1T     = (float*)(ws + 170393600);       // 262144
  float* W2T     = (float*)(ws + 170655744);       // 262144

  k_pre<<<dim3(66176), 256, 0, stream>>>(inputs, lin_g, lin_b, x,
                                         Wq, Wv, W_ih, W_hh, W1, W2,
                                         WqT, WvT, WihT, WhhT, W1T, W2T);
  k_qw0<<<dim3(BATCH, 8), 256, 0, stream>>>(smu, slsig, noise, lsl_g, lsl_b,
                                            WqT, Wk, out, qwb);
  for (int it = 0; it < 3; ++it) {
    k_att<<<dim3(64, BATCH), 256, 0, stream>>>(x, qwb, stats, axp);
    k_update3<<<dim3(BATCH, 2), 512, 0, stream>>>(
        axp, stats, out, WvT, WihT, WhhT, b_ih, b_hh, W1T, b1, W2T, b2,
        lml_g, lml_b, lsl_g, lsl_b, WqT, Wk, qwb, (it < 2) ? 1 : 0, out);
  }
}